// Round 4
// baseline (804.947 us; speedup 1.0000x reference)
//
#include <hip/hip_runtime.h>
#include <cstdint>
#include <cstddef>

// Problem constants
#define B_ 4
#define T_ 2048
#define C_ 1024
#define H_ 16
#define D_ 64

typedef __attribute__((ext_vector_type(8))) __bf16 bf16x8;
typedef __attribute__((ext_vector_type(4))) float floatx4;

__device__ __forceinline__ unsigned short f2bf(float f) {
  union { float f; unsigned int u; } v; v.f = f;
  unsigned int r = v.u + 0x7fffu + ((v.u >> 16) & 1u);  // RNE
  return (unsigned short)(r >> 16);
}
__device__ __forceinline__ ushort4 pk4(float a, float b, float c, float d) {
  ushort4 u; u.x = f2bf(a); u.y = f2bf(b); u.z = f2bf(c); u.w = f2bf(d);
  return u;
}

// C = A[M,1024] @ W[N,1024]^T + bias.  Inputs A (fp32 or bf16-gather), W fp32,
// bias fp32.  128x128 blocks, 4 waves of 64x64, 16x16x32 bf16 MFMA.
// GATHER==1: A is bf16 ctx in [BH=64, T=2048, D=64] layout; logical A[m,k]
//            with m=b*2048+t, k=h*64+d -> A[((b*16+h)*2048+t)*64+d].
// GATHER==0: A is fp32 row-major [M,1024] (converted to bf16 while staging).
// EPI==0: scatter bf16 into Q/K [BH,T,64] and V^T [BH,64,T].
// EPI==1: fp32 store to out[M,1024].
template<int EPI, int GATHER>
__global__ __launch_bounds__(256, 2)
void gemm_bt(const void* __restrict__ Araw,
             const float* __restrict__ W,
             const float* __restrict__ bias,
             float* __restrict__ out,
             unsigned short* __restrict__ qws,
             unsigned short* __restrict__ kws,
             unsigned short* __restrict__ vtws)
{
  alignas(16) __shared__ unsigned short As[128][72];  // BK=64 + pad 8
  alignas(16) __shared__ unsigned short Bs[128][72];
  const int tid  = threadIdx.x;
  const int lane = tid & 63;
  const int wid  = tid >> 6;
  const int col  = lane & 15;
  const int quad = lane >> 4;
  const int wm = (wid >> 1) << 6;
  const int wn = (wid & 1) << 6;
  const int bm = blockIdx.y << 7;
  const int bn = blockIdx.x << 7;

  const float* Af = (const float*)Araw;
  const unsigned short* Actx = (const unsigned short*)Araw;

  floatx4 acc[4][4];
#pragma unroll
  for (int i = 0; i < 4; ++i)
#pragma unroll
    for (int j = 0; j < 4; ++j)
      acc[i][j] = (floatx4){0.f, 0.f, 0.f, 0.f};

  for (int k0 = 0; k0 < 1024; k0 += 64) {
    __syncthreads();
#pragma unroll
    for (int s = 0; s < 4; ++s) {
      int c   = (s << 8) + tid;     // 0..1023 chunk id
      int row = c >> 3;             // 0..127
      int kc  = (c & 7) << 3;       // 0,8,..,56
      if (GATHER) {
        int m = bm + row, k = k0 + kc;
        int b = m >> 11, t = m & 2047, h = k >> 6, d = k & 63;
        *(uint4*)&As[row][kc] =
            *(const uint4*)&Actx[(((size_t)(b * 16 + h) * 2048 + t) << 6) + d];
      } else {
        const float* src = &Af[(size_t)(bm + row) * 1024 + k0 + kc];
        float4 f0 = *(const float4*)src;
        float4 f1 = *(const float4*)(src + 4);
        *(ushort4*)&As[row][kc]     = pk4(f0.x, f0.y, f0.z, f0.w);
        *(ushort4*)&As[row][kc + 4] = pk4(f1.x, f1.y, f1.z, f1.w);
      }
      const float* wsrc = &W[(size_t)(bn + row) * 1024 + k0 + kc];
      float4 w0 = *(const float4*)wsrc;
      float4 w1 = *(const float4*)(wsrc + 4);
      *(ushort4*)&Bs[row][kc]     = pk4(w0.x, w0.y, w0.z, w0.w);
      *(ushort4*)&Bs[row][kc + 4] = pk4(w1.x, w1.y, w1.z, w1.w);
    }
    __syncthreads();
#pragma unroll
    for (int kk = 0; kk < 64; kk += 32) {
      bf16x8 af[4], bfr[4];
#pragma unroll
      for (int i = 0; i < 4; ++i)
        af[i] = *(const bf16x8*)&As[wm + i * 16 + col][kk + quad * 8];
#pragma unroll
      for (int j = 0; j < 4; ++j)
        bfr[j] = *(const bf16x8*)&Bs[wn + j * 16 + col][kk + quad * 8];
#pragma unroll
      for (int i = 0; i < 4; ++i)
#pragma unroll
        for (int j = 0; j < 4; ++j)
          acc[i][j] = __builtin_amdgcn_mfma_f32_16x16x32_bf16(af[i], bfr[j], acc[i][j], 0, 0, 0);
    }
  }

  // Epilogue.  C/D layout: row = quad*4 + r, col = lane&15 (m89/m91).
#pragma unroll
  for (int i = 0; i < 4; ++i) {
    const int row = bm + wm + i * 16 + quad * 4;  // + r
#pragma unroll
    for (int j = 0; j < 4; ++j) {
      const int n  = bn + wn + j * 16 + col;
      const float bv = bias[n];
      float v[4];
#pragma unroll
      for (int r = 0; r < 4; ++r) v[r] = acc[i][j][r] + bv;

      if (EPI == 1) {
#pragma unroll
        for (int r = 0; r < 4; ++r)
          out[(size_t)(row + r) * 1024 + n] = v[r];
      } else {
        const int s   = n >> 10;        // 0=q 1=k 2=v
        const int rem = n & 1023;
        const int h   = rem >> 6;
        const int d   = rem & 63;
        const int b   = row >> 11;      // 128-row block never crosses a batch
        const int t   = row & 2047;
        const size_t bh = (size_t)(b * H_ + h);
        if (s == 0) {
#pragma unroll
          for (int r = 0; r < 4; ++r)
            qws[(bh * T_ + t + r) * D_ + d] = f2bf(v[r]);
        } else if (s == 1) {
#pragma unroll
          for (int r = 0; r < 4; ++r)
            kws[(bh * T_ + t + r) * D_ + d] = f2bf(v[r]);
        } else {
          *(ushort4*)&vtws[(bh * D_ + d) * T_ + t] = pk4(v[0], v[1], v[2], v[3]);
        }
      }
    }
  }
}

// Flash-style causal attention (all-bf16 internal).  Block = 64 consecutive
// Q rows of one (b,h); 4 waves each own 16 rows.  Block-uniform tile count so
// __syncthreads() is legal; fully-masked extra tiles are no-ops under online
// softmax.  Output written in-place over the Q rows ([BH,T,64] layout).
__global__ void attn_causal(unsigned short* __restrict__ qws,
                            const unsigned short* __restrict__ kws,
                            const unsigned short* __restrict__ vtws)
{
  alignas(16) __shared__ unsigned short P_all[4][16][40];  // 16q x 32k (+8 pad)
  const int tid  = threadIdx.x;
  const int lane = tid & 63;
  const int wid  = tid >> 6;
  const int col  = lane & 15;
  const int quad = lane >> 4;

  const int bh    = blockIdx.x >> 5;          // (b*16+h), 0..63
  const int qbase = (blockIdx.x & 31) << 6;   // 0,64,...,1984
  const int q0    = qbase + (wid << 4);       // this wave's 16-row tile

  unsigned short* Qp = qws + ((size_t)bh * T_ + q0) * D_;
  const unsigned short* Kp = kws + (size_t)bh * T_ * D_;
  const unsigned short* Vp = vtws + (size_t)bh * D_ * T_;
  unsigned short (*psh)[40] = P_all[wid];

  // Q fragments persist: A[m=col][k=quad*8+j], two Dh halves
  const bf16x8 aq0 = *(const bf16x8*)&Qp[col * D_ + quad * 8];
  const bf16x8 aq1 = *(const bf16x8*)&Qp[col * D_ + 32 + quad * 8];

  floatx4 o[4];
#pragma unroll
  for (int j = 0; j < 4; ++j) o[j] = (floatx4){0.f, 0.f, 0.f, 0.f};
  float m[4], l[4];
#pragma unroll
  for (int r = 0; r < 4; ++r) { m[r] = -1e30f; l[r] = 0.f; }

  const float scl = 0.125f * 1.44269504088896f;  // 1/sqrt(64) * log2(e)
  const int nk = (qbase >> 5) + 2;  // block-uniform: covers rows qbase..qbase+63

  for (int kt = 0; kt < nk; ++kt) {
    const int kt0 = kt << 5;
    floatx4 s0 = (floatx4){0.f, 0.f, 0.f, 0.f};
    floatx4 s1 = (floatx4){0.f, 0.f, 0.f, 0.f};
    {
      bf16x8 bk;
      bk = *(const bf16x8*)&Kp[(size_t)(kt0 + col) * D_ + quad * 8];
      s0 = __builtin_amdgcn_mfma_f32_16x16x32_bf16(aq0, bk, s0, 0, 0, 0);
      bk = *(const bf16x8*)&Kp[(size_t)(kt0 + col) * D_ + 32 + quad * 8];
      s0 = __builtin_amdgcn_mfma_f32_16x16x32_bf16(aq1, bk, s0, 0, 0, 0);
      bk = *(const bf16x8*)&Kp[(size_t)(kt0 + 16 + col) * D_ + quad * 8];
      s1 = __builtin_amdgcn_mfma_f32_16x16x32_bf16(aq0, bk, s1, 0, 0, 0);
      bk = *(const bf16x8*)&Kp[(size_t)(kt0 + 16 + col) * D_ + 32 + quad * 8];
      s1 = __builtin_amdgcn_mfma_f32_16x16x32_bf16(aq1, bk, s1, 0, 0, 0);
    }
#pragma unroll
    for (int r = 0; r < 4; ++r) { s0[r] *= scl; s1[r] *= scl; }

    if (kt0 + 31 > q0) {  // partial or fully-masked tile
      const int rowg = q0 + quad * 4;
#pragma unroll
      for (int r = 0; r < 4; ++r) {
        if (kt0 + col > rowg + r)      s0[r] = -1e30f;
        if (kt0 + 16 + col > rowg + r) s1[r] = -1e30f;
      }
    }

    float p0[4], p1[4];
#pragma unroll
    for (int r = 0; r < 4; ++r) {
      float t = fmaxf(s0[r], s1[r]);
      t = fmaxf(t, __shfl_xor(t, 1));
      t = fmaxf(t, __shfl_xor(t, 2));
      t = fmaxf(t, __shfl_xor(t, 4));
      t = fmaxf(t, __shfl_xor(t, 8));
      const float mn = fmaxf(m[r], t);
      const float alpha = exp2f(m[r] - mn);
      p0[r] = exp2f(s0[r] - mn);
      p1[r] = exp2f(s1[r] - mn);
      float su = p0[r] + p1[r];
      su += __shfl_xor(su, 1);
      su += __shfl_xor(su, 2);
      su += __shfl_xor(su, 4);
      su += __shfl_xor(su, 8);
      l[r] = l[r] * alpha + su;
      m[r] = mn;
#pragma unroll
      for (int j = 0; j < 4; ++j) o[j][r] *= alpha;
    }

    // WAR: previous iteration's P-reads must retire before overwrite.
    __syncthreads();
#pragma unroll
    for (int r = 0; r < 4; ++r) {
      psh[quad * 4 + r][col]      = f2bf(p0[r]);
      psh[quad * 4 + r][16 + col] = f2bf(p1[r]);
    }
    // RAW: all lanes' P-writes visible before A-operand read.
    __syncthreads();

    bf16x8 ap = *(const bf16x8*)&psh[col][quad * 8];
#pragma unroll
    for (int j = 0; j < 4; ++j) {
      bf16x8 bv = *(const bf16x8*)&Vp[(size_t)(j * 16 + col) * T_ + kt0 + quad * 8];
      o[j] = __builtin_amdgcn_mfma_f32_16x16x32_bf16(ap, bv, o[j], 0, 0, 0);
    }
  }

  // Write ctx in-place over this wave's Q rows: [BH, T, 64] layout.
#pragma unroll
  for (int j = 0; j < 4; ++j) {
#pragma unroll
    for (int r = 0; r < 4; ++r) {
      const float v = o[j][r] / l[r];
      Qp[(size_t)(quad * 4 + r) * D_ + j * 16 + col] = f2bf(v);
    }
  }
}

extern "C" void kernel_launch(void* const* d_in, const int* in_sizes, int n_in,
                              void* d_out, int out_size, void* d_ws, size_t ws_size,
                              hipStream_t stream) {
  const float* x     = (const float*)d_in[0];  // [B,T,C] fp32
  // d_in[1] = causal mask (int32) -- statically known, unused
  const float* W_qkv = (const float*)d_in[2];  // [3C,C] fp32
  const float* b_qkv = (const float*)d_in[3];  // [3C]
  const float* W_out = (const float*)d_in[4];  // [C,C]
  const float* b_out = (const float*)d_in[5];  // [C]
  float* out = (float*)d_out;                  // [B,T,C] fp32 (32 MB)

  // Workspace layout (32 MB of d_ws used):
  //   qws  (Q bf16, then ctx in-place) : d_ws + 0      (16 MB)
  //   vtws (V^T bf16)                  : d_ws + 16 MB  (16 MB)
  //   kws  (K bf16)                    : d_out          (16 MB of its 32 MB)
  // K's lifetime ends when attention finishes; the out-projection then
  // overwrites d_out with the final fp32 result (stream-ordered).
  const size_t per = (size_t)B_ * H_ * T_ * D_;  // 8M elements
  unsigned short* qws  = (unsigned short*)d_ws;
  unsigned short* vtws = qws + per;
  unsigned short* kws  = (unsigned short*)d_out;

  // 1) QKV projection: [8192,1024] @ [3072,1024]^T -> scatter Q,K,V^T (bf16)
  gemm_bt<0, 0><<<dim3(3072 / 128, 8192 / 128), 256, 0, stream>>>(
      (const void*)x, W_qkv, b_qkv, nullptr, qws, kws, vtws);

  // 2) causal flash attention; ctx overwrites qws in [BH,T,64] layout
  attn_causal<<<dim3(B_ * H_ * (T_ / 64)), 256, 0, stream>>>(qws, kws, vtws);

  // 3) output projection: gather-A(bf16) [8192,1024] @ [1024,1024]^T -> fp32 out
  gemm_bt<1, 1><<<dim3(1024 / 128, 8192 / 128), 256, 0, stream>>>(
      (const void*)qws, W_out, b_out, out, nullptr, nullptr, nullptr);
}

// Round 6
// 579.137 us; speedup vs baseline: 1.3899x; 1.3899x over previous
//
#include <hip/hip_runtime.h>
#include <cstdint>
#include <cstddef>

// Problem constants
#define B_ 4
#define T_ 2048
#define C_ 1024
#define H_ 16
#define D_ 64

typedef __attribute__((ext_vector_type(8))) __bf16 bf16x8;
typedef __attribute__((ext_vector_type(4))) float floatx4;

#define QSCL (0.125f * 1.44269504088896f)  // 1/sqrt(64) * log2(e), folded into Q

__device__ __forceinline__ unsigned short f2bf(float f) {
  union { float f; unsigned int u; } v; v.f = f;
  unsigned int r = v.u + 0x7fffu + ((v.u >> 16) & 1u);  // RNE
  return (unsigned short)(r >> 16);
}
__device__ __forceinline__ ushort4 pk4(float a, float b, float c, float d) {
  ushort4 u; u.x = f2bf(a); u.y = f2bf(b); u.z = f2bf(c); u.w = f2bf(d);
  return u;
}

// C = A[M,1024] @ W[N,1024]^T + bias.  Inputs A (fp32 or bf16-gather), W fp32,
// bias fp32.  128x128 blocks, 4 waves of 64x64, 16x16x32 bf16 MFMA.
// GATHER==1: A is bf16 ctx in [BH=64, T=2048, D=64] layout.
// EPI==0: scatter bf16 into Q (pre-scaled by QSCL) / K [BH,T,64], V^T [BH,64,T].
// EPI==1: fp32 store to out[M,1024].
template<int EPI, int GATHER>
__global__ __launch_bounds__(256, 2)
void gemm_bt(const void* __restrict__ Araw,
             const float* __restrict__ W,
             const float* __restrict__ bias,
             float* __restrict__ out,
             unsigned short* __restrict__ qws,
             unsigned short* __restrict__ kws,
             unsigned short* __restrict__ vtws)
{
  alignas(16) __shared__ unsigned short As[128][72];  // BK=64 + pad 8
  alignas(16) __shared__ unsigned short Bs[128][72];
  const int tid  = threadIdx.x;
  const int lane = tid & 63;
  const int wid  = tid >> 6;
  const int col  = lane & 15;
  const int quad = lane >> 4;
  const int wm = (wid >> 1) << 6;
  const int wn = (wid & 1) << 6;
  const int bm = blockIdx.y << 7;
  const int bn = blockIdx.x << 7;

  const float* Af = (const float*)Araw;
  const unsigned short* Actx = (const unsigned short*)Araw;

  floatx4 acc[4][4];
#pragma unroll
  for (int i = 0; i < 4; ++i)
#pragma unroll
    for (int j = 0; j < 4; ++j)
      acc[i][j] = (floatx4){0.f, 0.f, 0.f, 0.f};

  for (int k0 = 0; k0 < 1024; k0 += 64) {
    __syncthreads();
#pragma unroll
    for (int s = 0; s < 4; ++s) {
      int c   = (s << 8) + tid;     // 0..1023 chunk id
      int row = c >> 3;             // 0..127
      int kc  = (c & 7) << 3;       // 0,8,..,56
      if (GATHER) {
        int m = bm + row, k = k0 + kc;
        int b = m >> 11, t = m & 2047, h = k >> 6, d = k & 63;
        *(uint4*)&As[row][kc] =
            *(const uint4*)&Actx[(((size_t)(b * 16 + h) * 2048 + t) << 6) + d];
      } else {
        const float* src = &Af[(size_t)(bm + row) * 1024 + k0 + kc];
        float4 f0 = *(const float4*)src;
        float4 f1 = *(const float4*)(src + 4);
        *(ushort4*)&As[row][kc]     = pk4(f0.x, f0.y, f0.z, f0.w);
        *(ushort4*)&As[row][kc + 4] = pk4(f1.x, f1.y, f1.z, f1.w);
      }
      const float* wsrc = &W[(size_t)(bn + row) * 1024 + k0 + kc];
      float4 w0 = *(const float4*)wsrc;
      float4 w1 = *(const float4*)(wsrc + 4);
      *(ushort4*)&Bs[row][kc]     = pk4(w0.x, w0.y, w0.z, w0.w);
      *(ushort4*)&Bs[row][kc + 4] = pk4(w1.x, w1.y, w1.z, w1.w);
    }
    __syncthreads();
#pragma unroll
    for (int kk = 0; kk < 64; kk += 32) {
      bf16x8 af[4], bfr[4];
#pragma unroll
      for (int i = 0; i < 4; ++i)
        af[i] = *(const bf16x8*)&As[wm + i * 16 + col][kk + quad * 8];
#pragma unroll
      for (int j = 0; j < 4; ++j)
        bfr[j] = *(const bf16x8*)&Bs[wn + j * 16 + col][kk + quad * 8];
#pragma unroll
      for (int i = 0; i < 4; ++i)
#pragma unroll
        for (int j = 0; j < 4; ++j)
          acc[i][j] = __builtin_amdgcn_mfma_f32_16x16x32_bf16(af[i], bfr[j], acc[i][j], 0, 0, 0);
    }
  }

  // Epilogue.  C/D layout: row = quad*4 + r, col = lane&15 (m89/m91).
#pragma unroll
  for (int i = 0; i < 4; ++i) {
    const int row = bm + wm + i * 16 + quad * 4;  // + r
#pragma unroll
    for (int j = 0; j < 4; ++j) {
      const int n  = bn + wn + j * 16 + col;
      const float bv = bias[n];
      float v[4];
#pragma unroll
      for (int r = 0; r < 4; ++r) v[r] = acc[i][j][r] + bv;

      if (EPI == 1) {
#pragma unroll
        for (int r = 0; r < 4; ++r)
          out[(size_t)(row + r) * 1024 + n] = v[r];
      } else {
        const int s   = n >> 10;        // 0=q 1=k 2=v
        const int rem = n & 1023;
        const int h   = rem >> 6;
        const int d   = rem & 63;
        const int b   = row >> 11;      // 128-row block never crosses a batch
        const int t   = row & 2047;
        const size_t bh = (size_t)(b * H_ + h);
        if (s == 0) {
#pragma unroll
          for (int r = 0; r < 4; ++r)
            qws[(bh * T_ + t + r) * D_ + d] = f2bf(v[r] * QSCL);
        } else if (s == 1) {
#pragma unroll
          for (int r = 0; r < 4; ++r)
            kws[(bh * T_ + t + r) * D_ + d] = f2bf(v[r]);
        } else {
          *(ushort4*)&vtws[(bh * D_ + d) * T_ + t] = pk4(v[0], v[1], v[2], v[3]);
        }
      }
    }
  }
}

// Flash-style causal attention, S^T formulation.  One wave per 16 Q rows,
// fully independent waves (no __syncthreads).  S^T = K.Q^T puts each query
// row in a single lane (lane holds S^T[key=quad*4+r][q=col]), so softmax
// state is lane-scalar and row reduction is 2 shuffles (xor 16/32).
// P staged through wave-private LDS (2x ds_write_b64 -> 1x ds_read_b128) to
// convert to the PV A-operand layout.  Output in-place over the Q rows.
// Grid: 32 blocks per (b,h) [4 tiles/block] x 64 bh = 2048 blocks.
__global__ __launch_bounds__(256)
void attn_causal(unsigned short* __restrict__ qws,
                 const unsigned short* __restrict__ kws,
                 const unsigned short* __restrict__ vtws)
{
  alignas(16) __shared__ unsigned short P_all[4][16][40];  // row stride 80 B
  const int tid  = threadIdx.x;
  const int lane = tid & 63;
  const int wid  = tid >> 6;
  const int col  = lane & 15;
  const int quad = lane >> 4;

  const int bh = blockIdx.x >> 5;        // (b*16+h), 0..63
  const int pr = blockIdx.x & 31;        // 0..31
  // Load-balance: pair short diagonals with long ones inside a block
  // (block total ~130 tiles of work for every pr).
  int tile;
  if      (wid == 0) tile = 2 * pr;
  else if (wid == 1) tile = 2 * pr + 1;
  else if (wid == 2) tile = 127 - 2 * pr;
  else               tile = 126 - 2 * pr;
  const int q0 = tile << 4;

  unsigned short* Qp = qws + ((size_t)bh * T_ + q0) * D_;
  const unsigned short* Kp = kws + (size_t)bh * T_ * D_;
  const unsigned short* Vp = vtws + (size_t)bh * D_ * T_;
  unsigned short (*psh)[40] = P_all[wid];

  // Q as B-operand: B[k=d=quad*8+j][n=q=col] = Q[q0+col][d]  (pre-scaled)
  const bf16x8 bq0 = *(const bf16x8*)&Qp[col * D_ + quad * 8];
  const bf16x8 bq1 = *(const bf16x8*)&Qp[col * D_ + 32 + quad * 8];

  floatx4 o[4];
#pragma unroll
  for (int j = 0; j < 4; ++j) o[j] = (floatx4){0.f, 0.f, 0.f, 0.f};
  float mrow = -1e30f, lrow = 0.f;   // per-lane state for q = q0+col

  const int nk = (q0 >> 5) + 1;      // exact per-wave tile count

  for (int kt = 0; kt < nk; ++kt) {
    const int kt0 = kt << 5;
    floatx4 s0 = (floatx4){0.f, 0.f, 0.f, 0.f};
    floatx4 s1 = (floatx4){0.f, 0.f, 0.f, 0.f};
    {
      bf16x8 ak;
      ak = *(const bf16x8*)&Kp[(size_t)(kt0 + col) * D_ + quad * 8];
      s0 = __builtin_amdgcn_mfma_f32_16x16x32_bf16(ak, bq0, s0, 0, 0, 0);
      ak = *(const bf16x8*)&Kp[(size_t)(kt0 + col) * D_ + 32 + quad * 8];
      s0 = __builtin_amdgcn_mfma_f32_16x16x32_bf16(ak, bq1, s0, 0, 0, 0);
      ak = *(const bf16x8*)&Kp[(size_t)(kt0 + 16 + col) * D_ + quad * 8];
      s1 = __builtin_amdgcn_mfma_f32_16x16x32_bf16(ak, bq0, s1, 0, 0, 0);
      ak = *(const bf16x8*)&Kp[(size_t)(kt0 + 16 + col) * D_ + 32 + quad * 8];
      s1 = __builtin_amdgcn_mfma_f32_16x16x32_bf16(ak, bq1, s1, 0, 0, 0);
    }
    // s0[r] = S^T[key=kt0+quad*4+r][q=q0+col], log2-domain (Q pre-scaled)

    if (kt == nk - 1) {  // only the last tile can cross the diagonal
      const int qg = q0 + col;
#pragma unroll
      for (int r = 0; r < 4; ++r) {
        if (kt0 + quad * 4 + r > qg)      s0[r] = -1e30f;
        if (kt0 + 16 + quad * 4 + r > qg) s1[r] = -1e30f;
      }
    }

    // Row max: 7 in-register + 2 cross-quad shuffles
    float t0 = fmaxf(fmaxf(s0[0], s0[1]), fmaxf(s0[2], s0[3]));
    float t1 = fmaxf(fmaxf(s1[0], s1[1]), fmaxf(s1[2], s1[3]));
    float t = fmaxf(t0, t1);
    t = fmaxf(t, __shfl_xor(t, 16));
    t = fmaxf(t, __shfl_xor(t, 32));
    const float mn = fmaxf(mrow, t);
    const float alpha = exp2f(mrow - mn);
    float p0[4], p1[4];
#pragma unroll
    for (int r = 0; r < 4; ++r) {
      p0[r] = exp2f(s0[r] - mn);
      p1[r] = exp2f(s1[r] - mn);
    }
    float su = (p0[0] + p0[1]) + (p0[2] + p0[3]) +
               (p1[0] + p1[1]) + (p1[2] + p1[3]);
    su += __shfl_xor(su, 16);
    su += __shfl_xor(su, 32);
    lrow = lrow * alpha + su;
    mrow = mn;

    // Rescale O (C-layout rows q=quad*4+r): fetch alpha of those rows.
    float ar[4];
#pragma unroll
    for (int r = 0; r < 4; ++r) ar[r] = __shfl(alpha, quad * 4 + r);
#pragma unroll
    for (int j = 0; j < 4; ++j)
#pragma unroll
      for (int r = 0; r < 4; ++r) o[j][r] *= ar[r];

    // Stage P: lane holds P[q=col][keys quad*4+r | 16+quad*4+r].
    // Wave-private LDS; DS pipe is in-order per wave (WAR safe); RAW needs
    // the explicit drain before the cross-lane read.
    *(ushort4*)&psh[col][quad * 4]      = pk4(p0[0], p0[1], p0[2], p0[3]);
    *(ushort4*)&psh[col][16 + quad * 4] = pk4(p1[0], p1[1], p1[2], p1[3]);
    asm volatile("s_waitcnt lgkmcnt(0)" ::: "memory");
    bf16x8 ap = *(const bf16x8*)&psh[col][quad * 8];  // A[m=q=col][k=quad*8+j]

#pragma unroll
    for (int j = 0; j < 4; ++j) {
      bf16x8 bv = *(const bf16x8*)&Vp[(size_t)(j * 16 + col) * T_ + kt0 + quad * 8];
      o[j] = __builtin_amdgcn_mfma_f32_16x16x32_bf16(ap, bv, o[j], 0, 0, 0);
    }
    asm volatile("s_waitcnt lgkmcnt(0)" ::: "memory");  // pin ap-read before next write
  }

  // Final 1/l (per row q=quad*4+r) and in-place write: [BH,T,64] layout.
  float lr[4];
#pragma unroll
  for (int r = 0; r < 4; ++r) lr[r] = 1.0f / __shfl(lrow, quad * 4 + r);
#pragma unroll
  for (int j = 0; j < 4; ++j)
#pragma unroll
    for (int r = 0; r < 4; ++r)
      Qp[(size_t)(quad * 4 + r) * D_ + j * 16 + col] = f2bf(o[j][r] * lr[r]);
}

extern "C" void kernel_launch(void* const* d_in, const int* in_sizes, int n_in,
                              void* d_out, int out_size, void* d_ws, size_t ws_size,
                              hipStream_t stream) {
  const float* x     = (const float*)d_in[0];  // [B,T,C] fp32
  // d_in[1] = causal mask (int32) -- statically known, unused
  const float* W_qkv = (const float*)d_in[2];  // [3C,C] fp32
  const float* b_qkv = (const float*)d_in[3];  // [3C]
  const float* W_out = (const float*)d_in[4];  // [C,C]
  const float* b_out = (const float*)d_in[5];  // [C]
  float* out = (float*)d_out;                  // [B,T,C] fp32 (32 MB)

  // Workspace layout (32 MB of d_ws used):
  //   qws  (Q bf16 prescaled, then ctx in-place) : d_ws + 0      (16 MB)
  //   vtws (V^T bf16)                            : d_ws + 16 MB  (16 MB)
  //   kws  (K bf16)                              : d_out          (16 MB)
  // K dies when attention finishes; out-projection then overwrites d_out.
  const size_t per = (size_t)B_ * H_ * T_ * D_;  // 8M elements
  unsigned short* qws  = (unsigned short*)d_ws;
  unsigned short* vtws = qws + per;
  unsigned short* kws  = (unsigned short*)d_out;

  // 1) QKV projection: [8192,1024] @ [3072,1024]^T -> scatter Q,K,V^T (bf16)
  gemm_bt<0, 0><<<dim3(3072 / 128, 8192 / 128), 256, 0, stream>>>(
      (const void*)x, W_qkv, b_qkv, nullptr, qws, kws, vtws);

  // 2) causal flash attention; ctx overwrites qws in [BH,T,64] layout
  // Grid: 64 bh x 32 block-pairs = 2048 blocks (4 tiles per block).
  attn_causal<<<dim3(B_ * H_ * (T_ / 64)), 256, 0, stream>>>(qws, kws, vtws);

  // 3) output projection: gather-A(bf16) [8192,1024] @ [1024,1024]^T -> fp32 out
  gemm_bt<1, 1><<<dim3(1024 / 128, 8192 / 128), 256, 0, stream>>>(
      (const void*)qws, W_out, b_out, out, nullptr, nullptr, nullptr);
}

// Round 7
// 544.635 us; speedup vs baseline: 1.4780x; 1.0633x over previous
//
#include <hip/hip_runtime.h>
#include <cstdint>
#include <cstddef>

// Problem constants
#define B_ 4
#define T_ 2048
#define C_ 1024
#define H_ 16
#define D_ 64

typedef __attribute__((ext_vector_type(8))) __bf16 bf16x8;
typedef __attribute__((ext_vector_type(4))) float floatx4;

#define QSCL (0.125f * 1.44269504088896f)  // 1/sqrt(64) * log2(e), folded into Q

__device__ __forceinline__ unsigned short f2bf(float f) {
  union { float f; unsigned int u; } v; v.f = f;
  unsigned int r = v.u + 0x7fffu + ((v.u >> 16) & 1u);  // RNE
  return (unsigned short)(r >> 16);
}
__device__ __forceinline__ ushort4 pk4(float a, float b, float c, float d) {
  ushort4 u; u.x = f2bf(a); u.y = f2bf(b); u.z = f2bf(c); u.w = f2bf(d);
  return u;
}

// C = A[M,1024] @ W[N,1024]^T + bias.  Inputs A (fp32 or bf16-gather), W fp32,
// bias fp32.  128x128 blocks, 4 waves of 64x64, 16x16x32 bf16 MFMA.
// GATHER==1: A is bf16 ctx in [BH=64, T=2048, D=64] layout.
// EPI==0: scatter bf16 into Q (pre-scaled by QSCL) / K [BH,T,64], V^T [BH,64,T].
// EPI==1: fp32 store to out[M,1024].
template<int EPI, int GATHER>
__global__ __launch_bounds__(256, 2)
void gemm_bt(const void* __restrict__ Araw,
             const float* __restrict__ W,
             const float* __restrict__ bias,
             float* __restrict__ out,
             unsigned short* __restrict__ qws,
             unsigned short* __restrict__ kws,
             unsigned short* __restrict__ vtws)
{
  alignas(16) __shared__ unsigned short As[128][72];  // BK=64 + pad 8
  alignas(16) __shared__ unsigned short Bs[128][72];
  const int tid  = threadIdx.x;
  const int lane = tid & 63;
  const int wid  = tid >> 6;
  const int col  = lane & 15;
  const int quad = lane >> 4;
  const int wm = (wid >> 1) << 6;
  const int wn = (wid & 1) << 6;
  const int bm = blockIdx.y << 7;
  const int bn = blockIdx.x << 7;

  const float* Af = (const float*)Araw;
  const unsigned short* Actx = (const unsigned short*)Araw;

  floatx4 acc[4][4];
#pragma unroll
  for (int i = 0; i < 4; ++i)
#pragma unroll
    for (int j = 0; j < 4; ++j)
      acc[i][j] = (floatx4){0.f, 0.f, 0.f, 0.f};

  for (int k0 = 0; k0 < 1024; k0 += 64) {
    __syncthreads();
#pragma unroll
    for (int s = 0; s < 4; ++s) {
      int c   = (s << 8) + tid;     // 0..1023 chunk id
      int row = c >> 3;             // 0..127
      int kc  = (c & 7) << 3;       // 0,8,..,56
      if (GATHER) {
        int m = bm + row, k = k0 + kc;
        int b = m >> 11, t = m & 2047, h = k >> 6, d = k & 63;
        *(uint4*)&As[row][kc] =
            *(const uint4*)&Actx[(((size_t)(b * 16 + h) * 2048 + t) << 6) + d];
      } else {
        const float* src = &Af[(size_t)(bm + row) * 1024 + k0 + kc];
        float4 f0 = *(const float4*)src;
        float4 f1 = *(const float4*)(src + 4);
        *(ushort4*)&As[row][kc]     = pk4(f0.x, f0.y, f0.z, f0.w);
        *(ushort4*)&As[row][kc + 4] = pk4(f1.x, f1.y, f1.z, f1.w);
      }
      const float* wsrc = &W[(size_t)(bn + row) * 1024 + k0 + kc];
      float4 w0 = *(const float4*)wsrc;
      float4 w1 = *(const float4*)(wsrc + 4);
      *(ushort4*)&Bs[row][kc]     = pk4(w0.x, w0.y, w0.z, w0.w);
      *(ushort4*)&Bs[row][kc + 4] = pk4(w1.x, w1.y, w1.z, w1.w);
    }
    __syncthreads();
#pragma unroll
    for (int kk = 0; kk < 64; kk += 32) {
      bf16x8 af[4], bfr[4];
#pragma unroll
      for (int i = 0; i < 4; ++i)
        af[i] = *(const bf16x8*)&As[wm + i * 16 + col][kk + quad * 8];
#pragma unroll
      for (int j = 0; j < 4; ++j)
        bfr[j] = *(const bf16x8*)&Bs[wn + j * 16 + col][kk + quad * 8];
#pragma unroll
      for (int i = 0; i < 4; ++i)
#pragma unroll
        for (int j = 0; j < 4; ++j)
          acc[i][j] = __builtin_amdgcn_mfma_f32_16x16x32_bf16(af[i], bfr[j], acc[i][j], 0, 0, 0);
    }
  }

  // Epilogue.  C/D layout: row = quad*4 + r, col = lane&15 (m89/m91).
#pragma unroll
  for (int i = 0; i < 4; ++i) {
    const int row = bm + wm + i * 16 + quad * 4;  // + r
#pragma unroll
    for (int j = 0; j < 4; ++j) {
      const int n  = bn + wn + j * 16 + col;
      const float bv = bias[n];
      float v[4];
#pragma unroll
      for (int r = 0; r < 4; ++r) v[r] = acc[i][j][r] + bv;

      if (EPI == 1) {
#pragma unroll
        for (int r = 0; r < 4; ++r)
          out[(size_t)(row + r) * 1024 + n] = v[r];
      } else {
        const int s   = n >> 10;        // 0=q 1=k 2=v
        const int rem = n & 1023;
        const int h   = rem >> 6;
        const int d   = rem & 63;
        const int b   = row >> 11;      // 128-row block never crosses a batch
        const int t   = row & 2047;
        const size_t bh = (size_t)(b * H_ + h);
        if (s == 0) {
#pragma unroll
          for (int r = 0; r < 4; ++r)
            qws[(bh * T_ + t + r) * D_ + d] = f2bf(v[r] * QSCL);
        } else if (s == 1) {
#pragma unroll
          for (int r = 0; r < 4; ++r)
            kws[(bh * T_ + t + r) * D_ + d] = f2bf(v[r]);
        } else {
          *(ushort4*)&vtws[(bh * D_ + d) * T_ + t] = pk4(v[0], v[1], v[2], v[3]);
        }
      }
    }
  }
}

// Flash-style causal attention, S^T formulation, 64-key tiles, software-
// pipelined K prefetch.  One wave per 16 Q rows; waves independent (no
// __syncthreads).  Lane holds S^T[key=kt0+g*16+quad*4+r][q=q0+col] (4 key
// groups g); softmax state lane-scalar, row reduce = 2 shuffles.
// Pipeline: QK^T consumes kc[] -> V loads issue -> next-tile K loads re-fill
// kc[] (dead regs) -> softmax VALU overlaps loads -> LDS P round-trip -> PV.
__global__ __launch_bounds__(256)
void attn_causal(unsigned short* __restrict__ qws,
                 const unsigned short* __restrict__ kws,
                 const unsigned short* __restrict__ vtws)
{
  alignas(16) __shared__ unsigned short P_all[4][16][72];  // 16q x 64k (+8 pad)
  const int tid  = threadIdx.x;
  const int lane = tid & 63;
  const int wid  = tid >> 6;
  const int col  = lane & 15;
  const int quad = lane >> 4;

  const int bh = blockIdx.x >> 5;        // (b*16+h), 0..63
  const int pr = blockIdx.x & 31;        // 0..31
  // Load-balance: pair short diagonals with long ones inside a block.
  int tile;
  if      (wid == 0) tile = 2 * pr;
  else if (wid == 1) tile = 2 * pr + 1;
  else if (wid == 2) tile = 127 - 2 * pr;
  else               tile = 126 - 2 * pr;
  const int q0 = tile << 4;

  unsigned short* Qp = qws + ((size_t)bh * T_ + q0) * D_;
  const unsigned short* Kp = kws + (size_t)bh * T_ * D_;
  const unsigned short* Vp = vtws + (size_t)bh * D_ * T_;
  unsigned short (*psh)[72] = P_all[wid];

  // Q as B-operand: B[k=d=quad*8+j][n=q=col] = Q[q0+col][d]  (pre-scaled)
  const bf16x8 bq0 = *(const bf16x8*)&Qp[col * D_ + quad * 8];
  const bf16x8 bq1 = *(const bf16x8*)&Qp[col * D_ + 32 + quad * 8];

  floatx4 o[4];
#pragma unroll
  for (int j = 0; j < 4; ++j) o[j] = (floatx4){0.f, 0.f, 0.f, 0.f};
  float mrow = -1e30f, lrow = 0.f;   // per-lane state for q = q0+col

  const int nk = (q0 >> 6) + 1;      // 64-key tiles covering 0..q0+15

  // Lane-invariant parts of the K/V addresses.
  const unsigned short* Kl = Kp + (size_t)col * D_ + quad * 8;   // + (kt0+g*16)*D (+32)
  const unsigned short* Vl = Vp + (size_t)col * T_ + quad * 8;   // + j*16*T + kt0 (+32)

  // Preload K tile 0: kc[g*2+h] = K[kt0+g*16+col][h*32 + quad*8..]
  bf16x8 kc[8];
#pragma unroll
  for (int g = 0; g < 4; ++g) {
    kc[g * 2]     = *(const bf16x8*)&Kl[(size_t)(g * 16) * D_];
    kc[g * 2 + 1] = *(const bf16x8*)&Kl[(size_t)(g * 16) * D_ + 32];
  }

  for (int kt = 0; kt < nk; ++kt) {
    const int kt0 = kt << 6;
    // ---- QK^T: s[g] = S^T[keys kt0+g*16+quad*4+r][q=q0+col] ----
    floatx4 s[4];
#pragma unroll
    for (int g = 0; g < 4; ++g) {
      s[g] = (floatx4){0.f, 0.f, 0.f, 0.f};
      s[g] = __builtin_amdgcn_mfma_f32_16x16x32_bf16(kc[g * 2],     bq0, s[g], 0, 0, 0);
      s[g] = __builtin_amdgcn_mfma_f32_16x16x32_bf16(kc[g * 2 + 1], bq1, s[g], 0, 0, 0);
    }

    // ---- issue V loads for this tile (in flight through softmax) ----
    bf16x8 vv[8];
#pragma unroll
    for (int j = 0; j < 4; ++j) {
      vv[j * 2]     = *(const bf16x8*)&Vl[(size_t)(j * 16) * T_ + kt0];
      vv[j * 2 + 1] = *(const bf16x8*)&Vl[(size_t)(j * 16) * T_ + kt0 + 32];
    }

    // ---- prefetch next K tile into kc (dead after QK MFMAs) ----
    if (kt + 1 < nk) {
      const int ktn = (kt + 1) << 6;
#pragma unroll
      for (int g = 0; g < 4; ++g) {
        kc[g * 2]     = *(const bf16x8*)&Kl[(size_t)(ktn + g * 16) * D_];
        kc[g * 2 + 1] = *(const bf16x8*)&Kl[(size_t)(ktn + g * 16) * D_ + 32];
      }
    }

    // ---- causal mask (only last tile can cross the diagonal) ----
    if (kt == nk - 1) {
      const int qg = q0 + col;
#pragma unroll
      for (int g = 0; g < 4; ++g)
#pragma unroll
        for (int r = 0; r < 4; ++r)
          if (kt0 + g * 16 + quad * 4 + r > qg) s[g][r] = -1e30f;
    }

    // ---- online softmax (log2 domain; Q pre-scaled) ----
    float t01 = fmaxf(fmaxf(fmaxf(s[0][0], s[0][1]), fmaxf(s[0][2], s[0][3])),
                      fmaxf(fmaxf(s[1][0], s[1][1]), fmaxf(s[1][2], s[1][3])));
    float t23 = fmaxf(fmaxf(fmaxf(s[2][0], s[2][1]), fmaxf(s[2][2], s[2][3])),
                      fmaxf(fmaxf(s[3][0], s[3][1]), fmaxf(s[3][2], s[3][3])));
    float t = fmaxf(t01, t23);
    t = fmaxf(t, __shfl_xor(t, 16));
    t = fmaxf(t, __shfl_xor(t, 32));
    const float mn = fmaxf(mrow, t);
    const float alpha = exp2f(mrow - mn);
#pragma unroll
    for (int g = 0; g < 4; ++g)
#pragma unroll
      for (int r = 0; r < 4; ++r)
        s[g][r] = exp2f(s[g][r] - mn);   // P in place
    float su = ((s[0][0] + s[0][1]) + (s[0][2] + s[0][3])) +
               ((s[1][0] + s[1][1]) + (s[1][2] + s[1][3])) +
               ((s[2][0] + s[2][1]) + (s[2][2] + s[2][3])) +
               ((s[3][0] + s[3][1]) + (s[3][2] + s[3][3]));
    su += __shfl_xor(su, 16);
    su += __shfl_xor(su, 32);
    lrow = lrow * alpha + su;
    mrow = mn;

    // Rescale O (C-layout rows q=quad*4+r).
    float ar[4];
#pragma unroll
    for (int r = 0; r < 4; ++r) ar[r] = __shfl(alpha, quad * 4 + r);
#pragma unroll
    for (int j = 0; j < 4; ++j)
#pragma unroll
      for (int r = 0; r < 4; ++r) o[j][r] *= ar[r];

    // ---- P transpose via wave-private LDS ----
    // write: P[q=col][key kt0+g*16+quad*4+r]; DS pipe in-order per wave.
#pragma unroll
    for (int g = 0; g < 4; ++g)
      *(ushort4*)&psh[col][g * 16 + quad * 4] = pk4(s[g][0], s[g][1], s[g][2], s[g][3]);
    asm volatile("s_waitcnt lgkmcnt(0)" ::: "memory");
    const bf16x8 ap0 = *(const bf16x8*)&psh[col][quad * 8];       // keys 0..31
    const bf16x8 ap1 = *(const bf16x8*)&psh[col][32 + quad * 8];  // keys 32..63

    // ---- PV ----
#pragma unroll
    for (int j = 0; j < 4; ++j) {
      o[j] = __builtin_amdgcn_mfma_f32_16x16x32_bf16(ap0, vv[j * 2],     o[j], 0, 0, 0);
      o[j] = __builtin_amdgcn_mfma_f32_16x16x32_bf16(ap1, vv[j * 2 + 1], o[j], 0, 0, 0);
    }
  }

  // Final 1/l (per row q=quad*4+r) and in-place write: [BH,T,64] layout.
  float lr[4];
#pragma unroll
  for (int r = 0; r < 4; ++r) lr[r] = 1.0f / __shfl(lrow, quad * 4 + r);
#pragma unroll
  for (int j = 0; j < 4; ++j)
#pragma unroll
    for (int r = 0; r < 4; ++r)
      Qp[(size_t)(quad * 4 + r) * D_ + j * 16 + col] = f2bf(o[j][r] * lr[r]);
}

extern "C" void kernel_launch(void* const* d_in, const int* in_sizes, int n_in,
                              void* d_out, int out_size, void* d_ws, size_t ws_size,
                              hipStream_t stream) {
  const float* x     = (const float*)d_in[0];  // [B,T,C] fp32
  // d_in[1] = causal mask (int32) -- statically known, unused
  const float* W_qkv = (const float*)d_in[2];  // [3C,C] fp32
  const float* b_qkv = (const float*)d_in[3];  // [3C]
  const float* W_out = (const float*)d_in[4];  // [C,C]
  const float* b_out = (const float*)d_in[5];  // [C]
  float* out = (float*)d_out;                  // [B,T,C] fp32 (32 MB)

  // Workspace layout (32 MB of d_ws used):
  //   qws  (Q bf16 prescaled, then ctx in-place) : d_ws + 0      (16 MB)
  //   vtws (V^T bf16)                            : d_ws + 16 MB  (16 MB)
  //   kws  (K bf16)                              : d_out          (16 MB)
  // K dies when attention finishes; out-projection then overwrites d_out.
  const size_t per = (size_t)B_ * H_ * T_ * D_;  // 8M elements
  unsigned short* qws  = (unsigned short*)d_ws;
  unsigned short* vtws = qws + per;
  unsigned short* kws  = (unsigned short*)d_out;

  // 1) QKV projection: [8192,1024] @ [3072,1024]^T -> scatter Q,K,V^T (bf16)
  gemm_bt<0, 0><<<dim3(3072 / 128, 8192 / 128), 256, 0, stream>>>(
      (const void*)x, W_qkv, b_qkv, nullptr, qws, kws, vtws);

  // 2) causal flash attention; ctx overwrites qws in [BH,T,64] layout
  // Grid: 64 bh x 32 block-pairs = 2048 blocks (4 tiles per block).
  attn_causal<<<dim3(B_ * H_ * (T_ / 64)), 256, 0, stream>>>(qws, kws, vtws);

  // 3) output projection: gather-A(bf16) [8192,1024] @ [1024,1024]^T -> fp32 out
  gemm_bt<1, 1><<<dim3(1024 / 128, 8192 / 128), 256, 0, stream>>>(
      (const void*)qws, W_out, b_out, out, nullptr, nullptr, nullptr);
}